// Round 4
// baseline (274.186 us; speedup 1.0000x reference)
//
#include <hip/hip_runtime.h>
#include <math.h>

#define DIM 128
#define N_TOT 200
#define FDIM 384
#define NT 16
#define NTILES 13
#define KSTEPS 12
#define THREADS 512     // 8 waves; wave w owns d-rows [16w, 16w+16)

typedef __attribute__((ext_vector_type(8))) short short8;
typedef __attribute__((ext_vector_type(4))) float f32x4;

__device__ __forceinline__ unsigned short f2bf(float f) {
    unsigned int u = __float_as_uint(f);
    u += 0x7fffu + ((u >> 16) & 1u);          // RNE
    return (unsigned short)(u >> 16);
}
__device__ __forceinline__ float fast_tanh(float x) {
    return 1.f - 2.f / (__expf(2.f * x) + 1.f);
}

__global__ __launch_bounds__(THREADS, 4)
void acv_kernel(const int* __restrict__ xs_xt,        // [B][N][2]
                const int* __restrict__ path_idx,     // [B][N]
                const float* __restrict__ value_vocab,
                const float* __restrict__ path_vocab,
                const float* __restrict__ W,          // [128][384]
                const float* __restrict__ att_vec,
                const float* __restrict__ dense_w,    // [128][128]
                const float* __restrict__ dense_b,
                float* __restrict__ out)              // [B][128]
{
    // ctx tiles in MFMA-fragment granule order, bf16, triple-buffered.
    // granule(ks,row,g) 16B at ks*1024 + ((row*64 + g*16) ^ ((ks&1)<<6))
    __shared__ __align__(16) char ctx[3][NT * FDIM * 2];   // 3 x 12 KB
    __shared__ float spart[2][NT][8];
    __shared__ int   idx0[N_TOT], idx1[N_TOT], idxp[N_TOT];
    __shared__ float code_s[DIM];
    __shared__ float red[4][DIM];

    const int b    = blockIdx.x;
    const int tid  = threadIdx.x;
    const int wave = tid >> 6;
    const int lane = tid & 63;
    const int c    = lane & 15;       // MFMA row/col-within-16
    const int g    = lane >> 4;       // k-slot

    // ---- per-block index preload ----
    const int* xs_b = xs_xt + b * (N_TOT * 2);
    const int* p_b  = path_idx + b * N_TOT;
    for (int n = tid; n < N_TOT; n += THREADS) {
        idx0[n] = xs_b[2 * n];
        idx1[n] = xs_b[2 * n + 1];
        idxp[n] = p_b[n];
    }
    __syncthreads();

    // ---- staging: 1536 dwordx4 units per tile, 3 per thread, coalesced ----
    auto stage_issue = [&](int t, float4* pf) {
        const int t0 = t * NT;
        #pragma unroll
        for (int p = 0; p < 3; ++p) {
            int u   = tid + THREADS * p;      // 0..1535
            int s   = u >> 5;                 // segment id 0..47
            int off = u & 31;                 // dwordx4 within 512B segment
            int seg = s >> 4;                 // 0: xs0, 1: path, 2: xs1
            int nl  = s & 15;                 // local row
            int n   = t0 + nl; if (n > N_TOT - 1) n = N_TOT - 1;
            const float* src;
            if      (seg == 0) src = value_vocab + (size_t)idx0[n] * DIM;
            else if (seg == 1) src = path_vocab  + (size_t)idxp[n] * DIM;
            else               src = value_vocab + (size_t)idx1[n] * DIM;
            pf[p] = *(const float4*)(src + off * 4);
        }
    };
    auto stage_write = [&](int buf, const float4* pf) {
        #pragma unroll
        for (int p = 0; p < 3; ++p) {
            int u   = tid + THREADS * p;
            int s   = u >> 5, off = u & 31;
            int seg = s >> 4, nl  = s & 15;
            int f   = seg * 128 + off * 4;
            int ks  = f >> 5, gg = (f >> 3) & 3, h = (f >> 2) & 1;
            int byte = ks * 1024 + ((nl * 64 + gg * 16) ^ ((ks & 1) << 6)) + h * 8;
            float4 v = pf[p];
            unsigned int lo = ((unsigned)f2bf(v.y) << 16) | (unsigned)f2bf(v.x);
            unsigned int hi = ((unsigned)f2bf(v.w) << 16) | (unsigned)f2bf(v.z);
            *(uint2*)(ctx[buf] + byte) = make_uint2(lo, hi);
        }
    };

    float4 pf0[3], pf1[3];

    // ---- prologue: stage tile0, issue tiles 1,2 ----
    stage_issue(0, pf0);
    // W fragments into registers (once), overlapping pf0 latency
    short8 wfrag[KSTEPS];
    {
        const float* wrow = W + (size_t)(16 * wave + c) * FDIM + 8 * g;
        #pragma unroll
        for (int ks = 0; ks < KSTEPS; ++ks) {
            float4 q0 = *(const float4*)(wrow + 32 * ks);
            float4 q1 = *(const float4*)(wrow + 32 * ks + 4);
            short8 wv;
            wv[0] = (short)f2bf(q0.x); wv[1] = (short)f2bf(q0.y);
            wv[2] = (short)f2bf(q0.z); wv[3] = (short)f2bf(q0.w);
            wv[4] = (short)f2bf(q1.x); wv[5] = (short)f2bf(q1.y);
            wv[6] = (short)f2bf(q1.z); wv[7] = (short)f2bf(q1.w);
            wfrag[ks] = wv;
        }
    }
    const float a_val = att_vec[16 * wave + c];

    stage_write(0, pf0);          // waits pf0
    stage_issue(1, pf1);          // consumed at t=0
    stage_issue(2, pf0);          // consumed at t=1
    __syncthreads();              // tile0 visible

    float P = 0.f, L = 0.f;

    #pragma unroll
    for (int t = 0; t < NTILES; ++t) {
        // write tile t+1 (loaded 2 iters ago), re-issue same reg set for t+3
        if (t + 1 < NTILES) {
            float4 (&pfw)[3] = ((t + 1) & 1) ? pf1 : pf0;
            stage_write((t + 1) % 3, pfw);
            if (t + 3 < NTILES) stage_issue(t + 3, pfw);
        }

        // ---- MFMA: comb[16n x 16d-slice] ----
        const char* cb = ctx[t % 3];
        f32x4 acc = {0.f, 0.f, 0.f, 0.f};
        #pragma unroll
        for (int ks = 0; ks < KSTEPS; ++ks) {
            short8 af = *(const short8*)(cb + ks * 1024 + ((c * 64 + g * 16) ^ ((ks & 1) << 6)));
            acc = __builtin_amdgcn_mfma_f32_16x16x32_bf16(af, wfrag[ks], acc, 0, 0, 0);
        }

        // ---- tanh + partial scores (lane: comb[n=4g+r][d=16w+c]) ----
        float comb[4], sp[4];
        #pragma unroll
        for (int r = 0; r < 4; ++r) {
            comb[r] = fast_tanh(acc[r]);
            sp[r]   = comb[r] * a_val;
        }
        #pragma unroll
        for (int r = 0; r < 4; ++r) {
            sp[r] += __shfl_xor(sp[r], 1, 64);
            sp[r] += __shfl_xor(sp[r], 2, 64);
            sp[r] += __shfl_xor(sp[r], 4, 64);
            sp[r] += __shfl_xor(sp[r], 8, 64);
        }
        if (c == 0) {
            #pragma unroll
            for (int r = 0; r < 4; ++r) spart[t & 1][4 * g + r][wave] = sp[r];
        }
        __syncthreads();   // spart ready AND ctx[(t+1)%3] visible for next iter

        // ---- score finish + flash accumulation (|s| <= ~5: no max-sub) ----
        #pragma unroll
        for (int r = 0; r < 4; ++r) {
            int n = 4 * g + r;
            float4 s0 = *(const float4*)&spart[t & 1][n][0];
            float4 s1 = *(const float4*)&spart[t & 1][n][4];
            float s = ((s0.x + s0.y) + (s0.z + s0.w)) + ((s1.x + s1.y) + (s1.z + s1.w));
            float e = (t * NT + n < N_TOT) ? __expf(s) : 0.f;
            L += e;
            P = fmaf(e, comb[r], P);
        }
    }

    // ---- reduce over g; code = P/L ----
    P += __shfl_xor(P, 16, 64);
    P += __shfl_xor(P, 32, 64);
    L += __shfl_xor(L, 16, 64);
    L += __shfl_xor(L, 32, 64);
    if (g == 0) code_s[16 * wave + c] = P / L;
    __syncthreads();

    // ---- dense + sigmoid ----
    const int o   = tid & 127;
    const int seg = tid >> 7;
    float partial = 0.f;
    #pragma unroll 8
    for (int d = 32 * seg; d < 32 * seg + 32; ++d)
        partial = fmaf(code_s[d], dense_w[d * DIM + o], partial);
    red[seg][o] = partial;
    __syncthreads();
    if (tid < DIM) {
        float a2 = dense_b[tid] + ((red[0][tid] + red[1][tid]) + (red[2][tid] + red[3][tid]));
        out[(size_t)b * DIM + tid] = 1.f / (1.f + __expf(-a2));
    }
}

extern "C" void kernel_launch(void* const* d_in, const int* in_sizes, int n_in,
                              void* d_out, int out_size, void* d_ws, size_t ws_size,
                              hipStream_t stream) {
    const int*   xs_xt       = (const int*)d_in[0];
    const int*   path_idx    = (const int*)d_in[1];
    const float* value_vocab = (const float*)d_in[2];
    const float* path_vocab  = (const float*)d_in[3];
    const float* W           = (const float*)d_in[4];
    const float* att_vec     = (const float*)d_in[5];
    const float* dense_w     = (const float*)d_in[6];
    const float* dense_b     = (const float*)d_in[7];
    float*       out         = (float*)d_out;

    acv_kernel<<<1024, THREADS, 0, stream>>>(xs_xt, path_idx, value_vocab, path_vocab,
                                             W, att_vec, dense_w, dense_b, out);
}

// Round 5
// 114.790 us; speedup vs baseline: 2.3886x; 2.3886x over previous
//
#include <hip/hip_runtime.h>
#include <math.h>

#define DIM 128
#define N_TOT 200
#define FDIM 384
#define NT 16
#define NTILES 13
#define KSTEPS 12
#define THREADS 512     // 8 waves; wave w owns d-rows [16w, 16w+16)

typedef __attribute__((ext_vector_type(8))) short short8;
typedef __attribute__((ext_vector_type(4))) float f32x4;

__device__ __forceinline__ unsigned short f2bf(float f) {
    unsigned int u = __float_as_uint(f);
    u += 0x7fffu + ((u >> 16) & 1u);          // RNE
    return (unsigned short)(u >> 16);
}
__device__ __forceinline__ float fast_tanh(float x) {
    return 1.f - 2.f / (__expf(2.f * x) + 1.f);
}

__global__ __launch_bounds__(THREADS, 3)
void acv_kernel(const int* __restrict__ xs_xt,        // [B][N][2]
                const int* __restrict__ path_idx,     // [B][N]
                const float* __restrict__ value_vocab,
                const float* __restrict__ path_vocab,
                const float* __restrict__ W,          // [128][384]
                const float* __restrict__ att_vec,
                const float* __restrict__ dense_w,    // [128][128]
                const float* __restrict__ dense_b,
                float* __restrict__ out)              // [B][128]
{
    // ctx tiles in MFMA-fragment granule order, bf16, double-buffered.
    // granule(ks,row,g): 16B at ks*1024 + ((row*64 + g*16) ^ ((ks&1)<<6))
    __shared__ __align__(16) char ctx[2][NT * FDIM * 2];   // 2 x 12 KB
    __shared__ float spart[2][NT][8];
    __shared__ int   idx0[N_TOT], idx1[N_TOT], idxp[N_TOT];
    __shared__ float code_s[DIM];
    __shared__ float red[4][DIM];

    const int b    = blockIdx.x;
    const int tid  = threadIdx.x;
    const int wave = tid >> 6;
    const int lane = tid & 63;
    const int c    = lane & 15;       // MFMA row/col-within-16
    const int g    = lane >> 4;       // k-slot

    // ---- per-block index preload ----
    const int* xs_b = xs_xt + b * (N_TOT * 2);
    const int* p_b  = path_idx + b * N_TOT;
    for (int n = tid; n < N_TOT; n += THREADS) {
        idx0[n] = xs_b[2 * n];
        idx1[n] = xs_b[2 * n + 1];
        idxp[n] = p_b[n];
    }
    __syncthreads();

    // ---- staging: 1536 dwordx4 units per tile, 3 per thread, coalesced ----
    auto stage_issue = [&](int t, float4* pf) {
        const int t0 = t * NT;
        #pragma unroll
        for (int p = 0; p < 3; ++p) {
            int u   = tid + THREADS * p;      // 0..1535
            int s   = u >> 5;                 // segment id 0..47
            int off = u & 31;                 // dwordx4 within 512B segment
            int seg = s >> 4;                 // 0: xs0, 1: path, 2: xs1
            int nl  = s & 15;                 // local row
            int n   = t0 + nl; if (n > N_TOT - 1) n = N_TOT - 1;
            const float* src;
            if      (seg == 0) src = value_vocab + (size_t)idx0[n] * DIM;
            else if (seg == 1) src = path_vocab  + (size_t)idxp[n] * DIM;
            else               src = value_vocab + (size_t)idx1[n] * DIM;
            pf[p] = *(const float4*)(src + off * 4);
        }
    };
    auto stage_write = [&](char* base, const float4* pf) {
        #pragma unroll
        for (int p = 0; p < 3; ++p) {
            int u   = tid + THREADS * p;
            int s   = u >> 5, off = u & 31;
            int seg = s >> 4, nl  = s & 15;
            int f   = seg * 128 + off * 4;
            int ks  = f >> 5, gg = (f >> 3) & 3, h = (f >> 2) & 1;
            int byte = ks * 1024 + ((nl * 64 + gg * 16) ^ ((ks & 1) << 6)) + h * 8;
            float4 v = pf[p];
            unsigned int lo = ((unsigned)f2bf(v.y) << 16) | (unsigned)f2bf(v.x);
            unsigned int hi = ((unsigned)f2bf(v.w) << 16) | (unsigned)f2bf(v.z);
            *(uint2*)(base + byte) = make_uint2(lo, hi);
        }
    };

    float4 pfA[3];

    // ---- prologue ----
    stage_issue(0, pfA);
    // W fragments into registers (once), overlapping pfA latency
    short8 wfrag[KSTEPS];
    {
        const float* wrow = W + (size_t)(16 * wave + c) * FDIM + 8 * g;
        #pragma unroll
        for (int ks = 0; ks < KSTEPS; ++ks) {
            float4 q0 = *(const float4*)(wrow + 32 * ks);
            float4 q1 = *(const float4*)(wrow + 32 * ks + 4);
            short8 wv;
            wv[0] = (short)f2bf(q0.x); wv[1] = (short)f2bf(q0.y);
            wv[2] = (short)f2bf(q0.z); wv[3] = (short)f2bf(q0.w);
            wv[4] = (short)f2bf(q1.x); wv[5] = (short)f2bf(q1.y);
            wv[6] = (short)f2bf(q1.z); wv[7] = (short)f2bf(q1.w);
            wfrag[ks] = wv;
        }
    }
    const float a_val = att_vec[16 * wave + c];

    stage_write(ctx[0], pfA);     // waits pfA (tile 0)
    stage_issue(1, pfA);          // tile 1 in flight
    __syncthreads();              // tile 0 visible

    float P = 0.f, L = 0.f;
    float comb[4];

    auto do_tile = [&](int t) {
        const char* cb = ctx[t & 1];
        f32x4 acc = {0.f, 0.f, 0.f, 0.f};
        #pragma unroll
        for (int ks = 0; ks < KSTEPS; ++ks) {
            short8 af = *(const short8*)(cb + ks * 1024 + ((c * 64 + g * 16) ^ ((ks & 1) << 6)));
            acc = __builtin_amdgcn_mfma_f32_16x16x32_bf16(af, wfrag[ks], acc, 0, 0, 0);
        }
        float sp[4];
        #pragma unroll
        for (int r = 0; r < 4; ++r) {
            comb[r] = fast_tanh(acc[r]);
            sp[r]   = comb[r] * a_val;
        }
        #pragma unroll
        for (int r = 0; r < 4; ++r) {          // reduce over the 16 cols (c)
            sp[r] += __shfl_xor(sp[r], 1, 64);
            sp[r] += __shfl_xor(sp[r], 2, 64);
            sp[r] += __shfl_xor(sp[r], 4, 64);
            sp[r] += __shfl_xor(sp[r], 8, 64);
        }
        if (c == 0) {
            #pragma unroll
            for (int r = 0; r < 4; ++r) spart[t & 1][4 * g + r][wave] = sp[r];
        }
    };
    auto finish_tile = [&](int t) {
        #pragma unroll
        for (int r = 0; r < 4; ++r) {
            int n = 4 * g + r;
            float4 s0 = *(const float4*)&spart[t & 1][n][0];
            float4 s1 = *(const float4*)&spart[t & 1][n][4];
            float s = ((s0.x + s0.y) + (s0.z + s0.w)) + ((s1.x + s1.y) + (s1.z + s1.w));
            float e = (t * NT + n < N_TOT) ? __expf(s) : 0.f;   // |s|<=~5: no max-sub
            L += e;
            P = fmaf(e, comb[r], P);
        }
    };

    #pragma unroll 1
    for (int t = 0; t < NTILES; ++t) {
        do_tile(t);
        if (t + 1 < NTILES) {
            stage_write(ctx[(t + 1) & 1], pfA);     // tile t+1 (in flight since t-1/t)
            if (t + 2 < NTILES) stage_issue(t + 2, pfA);
        }
        __syncthreads();   // spart[t&1] ready AND ctx[(t+1)&1] visible
        finish_tile(t);
    }

    // ---- reduce over g; code = P/L ----
    P += __shfl_xor(P, 16, 64);
    P += __shfl_xor(P, 32, 64);
    L += __shfl_xor(L, 16, 64);
    L += __shfl_xor(L, 32, 64);
    if (g == 0) code_s[16 * wave + c] = P / L;
    __syncthreads();

    // ---- dense + sigmoid ----
    const int o   = tid & 127;
    const int seg = tid >> 7;
    float partial = 0.f;
    #pragma unroll 8
    for (int d = 32 * seg; d < 32 * seg + 32; ++d)
        partial = fmaf(code_s[d], dense_w[d * DIM + o], partial);
    red[seg][o] = partial;
    __syncthreads();
    if (tid < DIM) {
        float a2 = dense_b[tid] + ((red[0][tid] + red[1][tid]) + (red[2][tid] + red[3][tid]));
        out[(size_t)b * DIM + tid] = 1.f / (1.f + __expf(-a2));
    }
}

extern "C" void kernel_launch(void* const* d_in, const int* in_sizes, int n_in,
                              void* d_out, int out_size, void* d_ws, size_t ws_size,
                              hipStream_t stream) {
    const int*   xs_xt       = (const int*)d_in[0];
    const int*   path_idx    = (const int*)d_in[1];
    const float* value_vocab = (const float*)d_in[2];
    const float* path_vocab  = (const float*)d_in[3];
    const float* W           = (const float*)d_in[4];
    const float* att_vec     = (const float*)d_in[5];
    const float* dense_w     = (const float*)d_in[6];
    const float* dense_b     = (const float*)d_in[7];
    float*       out         = (float*)d_out;

    acv_kernel<<<1024, THREADS, 0, stream>>>(xs_xt, path_idx, value_vocab, path_vocab,
                                             W, att_vec, dense_w, dense_b, out);
}